// Round 5
// baseline (149.954 us; speedup 1.0000x reference)
//
#include <hip/hip_runtime.h>

#define DEV __device__ __forceinline__

typedef __attribute__((ext_vector_type(8))) short short8v;
typedef __attribute__((ext_vector_type(4))) float f32x4;

DEV unsigned short bfr(float f) {                 // fp32 -> bf16 RNE (weights)
    unsigned u = __float_as_uint(f);
    return (unsigned short)((u + 0x7fffu + ((u >> 16) & 1u)) >> 16);
}
DEV short bft(float f) { return (short)(__float_as_uint(f) >> 16); } // truncate (activations)
DEV float bf2f(unsigned short h) { return __uint_as_float(((unsigned)h) << 16); }
DEV float frcp(float x) { return __builtin_amdgcn_rcpf(x); }
DEV float ftanh(float x) { float e = __expf(2.0f * x); return 1.0f - 2.0f * frcp(e + 1.0f); }

constexpr int NN = 4096, TT = 128, RING = 32;
#define MFMA32(a, b, c) __builtin_amdgcn_mfma_f32_16x16x32_bf16(a, b, c, 0, 0, 0)

// Decoupled producer/consumer, 512 threads (R4 structure), with the scanner
// inner loop restructured per the R4 counter model:
//   MfmaUtil 10.4% over 4574 MFMA/block => ~19 cyc/MFMA per SIMD. The old
//   step split its 16 MFMAs into two groups of 8 with the h=0 VALU reduction
//   BETWEEN them in program order -> paid the MFMA-latency->VALU->MFMA round
//   trip twice (~1100 cyc/step, matching 70us/127 steps). NEW: issue all 16
//   MFMAs back-to-back into 16 live f32x4 accumulators (matrix pipe stays
//   fed, one latency round trip), then do both h reductions with split 4+4
//   fmaf chains. Predicted ~650-750 cyc/step.
// Register budget: waves_per_eu(2) at 512 thr = 256 VGPR/wave; D[16] adds
// +64 VGPR (~170 total, was 88). Watch WRITE_SIZE for spills (16KB = clean).
// R1-R3 LESSON kept: 1024-thread builds get a hard 64-VGPR cap -> 45MB
// scratch. R2 LESSON kept: no asm memory clobbers in hot loops.

__global__ __launch_bounds__(512) __attribute__((amdgpu_waves_per_eu(2)))
void wfa_kernel(
    const float* __restrict__ x,
    const float* __restrict__ e1w, const float* __restrict__ e1b,
    const float* __restrict__ e2w, const float* __restrict__ e2b,
    const float* __restrict__ A,
    const float* __restrict__ initw,
    const float* __restrict__ n1w, const float* __restrict__ n1b,
    const float* __restrict__ n2w, const float* __restrict__ n2b,
    const float* __restrict__ muw, const float* __restrict__ mub,
    const float* __restrict__ sgw, const float* __restrict__ sgb,
    const float* __restrict__ alw, const float* __restrict__ alb,
    float* __restrict__ out)
{
    __shared__ __align__(16) unsigned short enc_l[TT * 128];  // [t][n*8+d] bf16, 32KB
    __shared__ __align__(16) float x_l[16 * 130];             // [n][t]
    __shared__ __align__(16) short8v ring_l[RING][64];        // tmp frags, 32KB
    __shared__ __align__(16) float n1b_l[64], n2b_l[64], hb_l[48];
    __shared__ float part_l[8][16];
    __shared__ int head_l;     // items published by scanner
    __shared__ int ticket_l;   // next item index to hand out
    __shared__ int prog_l[7];  // per-consumer: all my ring reads < prog are done

    const int tid = threadIdx.x;
    const int wv = tid >> 6, lane = tid & 63;
    const int quad = lane >> 4, col = lane & 15;
    const int n0 = blockIdx.x * 16;
    const f32x4 z4 = {0.f, 0.f, 0.f, 0.f};

    // ---- stage x + biases + control ----
    for (int i = tid; i < 16 * TT; i += 512)
        x_l[(i >> 7) * 130 + (i & 127)] = x[(n0 + (i >> 7)) * TT + (i & 127)];
    if (tid < 64) { n1b_l[tid] = n1b[tid]; n2b_l[tid] = n2b[tid]; }
    if (tid >= 64 && tid < 112) {
        const int i = tid - 64, mt = i >> 4, k = i & 15;
        hb_l[i] = (k < 10) ? ((mt == 0) ? mub[k] : (mt == 1) ? sgb[k] : alb[k]) : 0.f;
    }
    if (tid >= 112 && tid < 119) prog_l[tid - 112] = 0;
    if (tid == 120) { head_l = 0; ticket_l = 0; }

    __syncthreads();   // x_l + control ready

    // ---- encoder: in-lane rank-1 layer1 + 2 MFMAs; wave wv owns t-tile wv ----
    {
        float e1c[16], e1bc[16];
        #pragma unroll
        for (int kc = 0; kc < 2; ++kc)
            #pragma unroll
            for (int jj = 0; jj < 8; ++jj) {
                const int f = kc * 32 + (jj >> 2) * 16 + quad * 4 + (jj & 3);
                e1c[kc * 8 + jj] = e1w[f];
                e1bc[kc * 8 + jj] = e1b[f];
            }
        short8v E2A[2];   // A[m=d(col<8)][k=h feature, permuted]
        #pragma unroll
        for (int kc = 0; kc < 2; ++kc)
            #pragma unroll
            for (int jj = 0; jj < 8; ++jj)
                E2A[kc][jj] = (short)(col < 8
                    ? bfr(e2w[(kc * 32 + (jj >> 2) * 16 + quad * 4 + (jj & 3)) * 8 + col]) : 0);
        float e2bc[4];
        #pragma unroll
        for (int r = 0; r < 4; ++r) e2bc[r] = (quad < 2) ? e2b[quad * 4 + r] : 0.f;

        const int tbase = wv * 16;
        #pragma unroll 1
        for (int nn = 0; nn < 16; ++nn) {
            const float xs = x_l[nn * 130 + tbase + col];
            short8v eB[2];
            #pragma unroll
            for (int kc = 0; kc < 2; ++kc)
                #pragma unroll
                for (int jj = 0; jj < 8; ++jj)
                    eB[kc][jj] = bft(fmaxf(fmaf(xs, e1c[kc * 8 + jj], e1bc[kc * 8 + jj]), 0.f));
            f32x4 d = MFMA32(E2A[0], eB[0], z4);
            d = MFMA32(E2A[1], eB[1], d);
            if (quad < 2) {
                #pragma unroll
                for (int r = 0; r < 4; ++r)
                    enc_l[(tbase + col) * 128 + nn * 8 + quad * 4 + r] = bfr(ftanh(d[r] + e2bc[r]));
            }
        }
    }
    __syncthreads();   // enc_l ready; last block-wide barrier until epilogue

    if (wv == 0) {
        // =========================== SCANNER ===========================
        short8v A2f[16];   // out m=mt*16+col -> d=mt>>1, j-half=mt&1; k=i (permuted)
        #pragma unroll
        for (int mt = 0; mt < 16; ++mt)
            #pragma unroll
            for (int jj = 0; jj < 8; ++jj)
                A2f[mt][jj] = (short)bfr(
                    A[((jj >> 2) * 16 + quad * 4 + (jj & 3)) * 256 + (mt >> 1) * 32 + (mt & 1) * 16 + col]);

        short8v tmpB;
        #pragma unroll
        for (int jj = 0; jj < 8; ++jj)
            tmpB[jj] = (short)bfr(initw[(jj >> 2) * 16 + quad * 4 + (jj & 3)]);

        asm volatile("s_setprio 2");   // win SIMD0 arbitration vs co-resident consumer

        short8v e8c = *(const short8v*)&enc_l[0 * 128 + col * 8];  // enc[0] for t=1

        #pragma unroll 1
        for (int t = 0; t < TT; ++t) {
            if (t > 0) {
                // prefetch enc[t] (used at t+1); waited only at e8c=e8n
                const short8v e8n = *(const short8v*)&enc_l[t * 128 + col * 8];
                float ev[8];
                #pragma unroll
                for (int d = 0; d < 8; ++d) ev[d] = bf2f((unsigned short)e8c[d]);
                // ALL 16 MFMAs back-to-back: matrix pipe pipelines at ~19cyc
                // each; only ONE result-latency wait before the reductions.
                f32x4 D[16];
                #pragma unroll
                for (int m = 0; m < 16; ++m) D[m] = MFMA32(A2f[m], tmpB, z4);
                short8v nt;
                #pragma unroll
                for (int h = 0; h < 2; ++h)
                    #pragma unroll
                    for (int r = 0; r < 4; ++r) {
                        // split 4+4 chains: dep tail ~4 fmaf, not 8
                        float sa = ev[0] * D[h][r];
                        float sb = ev[4] * D[8 + h][r];
                        #pragma unroll
                        for (int d = 1; d < 4; ++d) {
                            sa = fmaf(ev[d],     D[2 * d + h][r],     sa);
                            sb = fmaf(ev[d + 4], D[2 * d + 8 + h][r], sb);
                        }
                        nt[h * 4 + r] = bft(sa + sb);
                    }
                tmpB = nt;
                e8c = e8n;
            }
            ring_l[t & (RING - 1)][lane] = tmpB;
            if (t & 1) {
                __threadfence_block();                      // commit ring writes
                if (lane == 0) *(volatile int*)&head_l = t + 1;
            }
            if ((t & 7) == 7 && t >= RING - 1 && t < 120) {
                // next 8 writes hit slots of items t+1-RING..t+8-RING:
                // need min(prog) >= t+9-RING
                const int need = t + 9 - RING;
                while (true) {
                    int p = (lane < 7) ? *(volatile int*)&prog_l[lane] : (1 << 30);
                    #pragma unroll
                    for (int s = 1; s < 64; s <<= 1) {
                        const int q = __shfl_xor(p, s, 64);
                        p = (q < p) ? q : p;
                    }
                    if (p >= need) break;
                    __builtin_amdgcn_s_sleep(4);
                }
            }
        }
        if (lane < 16) part_l[0][lane] = 0.f;
    } else {
        // ========================== CONSUMERS ==========================
        short8v W1f[4];    // h1 out = mt*16+col, k = th feature (permuted)
        #pragma unroll
        for (int mt = 0; mt < 4; ++mt)
            #pragma unroll
            for (int jj = 0; jj < 8; ++jj)
                W1f[mt][jj] = (short)bfr(n1w[((jj >> 2) * 16 + quad * 4 + (jj & 3)) * 64 + mt * 16 + col]);
        short8v W2f[4][2];
        #pragma unroll
        for (int mt = 0; mt < 4; ++mt)
            #pragma unroll
            for (int kb = 0; kb < 2; ++kb)
                #pragma unroll
                for (int jj = 0; jj < 8; ++jj)
                    W2f[mt][kb][jj] = (short)bfr(
                        n2w[(kb * 32 + (jj >> 2) * 16 + quad * 4 + (jj & 3)) * 64 + mt * 16 + col]);
        short8v Whf[3][2]; // 0=mu,1=sig,2=alpha; out m = head idx (col<10)
        #pragma unroll
        for (int mt = 0; mt < 3; ++mt) {
            const float* Wh = (mt == 0) ? muw : (mt == 1) ? sgw : alw;
            #pragma unroll
            for (int kb = 0; kb < 2; ++kb)
                #pragma unroll
                for (int jj = 0; jj < 8; ++jj)
                    Whf[mt][kb][jj] = (short)(col < 10
                        ? bfr(Wh[(kb * 32 + (jj >> 2) * 16 + quad * 4 + (jj & 3)) * 10 + col]) : 0);
        }

        float res2 = 0.f;
        const float CST = 0.91893853320467274f;
        const int c = wv - 1;

        int t;
        if (lane == 0) { t = atomicAdd(&ticket_l, 1); *(volatile int*)&prog_l[c] = t; }
        t = __shfl(t, 0, 64);

        while (t < TT) {
            // ACQUIRE: orders the ring read after the observed head bump,
            // in compiler and HW, without an all-memory asm clobber.
            while (__hip_atomic_load(&head_l, __ATOMIC_ACQUIRE,
                                     __HIP_MEMORY_SCOPE_WORKGROUP) <= t)
                __builtin_amdgcn_s_sleep(1);
            const short8v tf = ring_l[t & (RING - 1)][lane];
            __threadfence_block();           // ring read complete before prog bump
            int tn;
            if (lane == 0) { tn = atomicAdd(&ticket_l, 1); *(volatile int*)&prog_l[c] = tn; }
            tn = __shfl(tn, 0, 64);

            short8v thB;
            #pragma unroll
            for (int jj = 0; jj < 8; ++jj)
                thB[jj] = bft(ftanh(bf2f((unsigned short)tf[jj])));

            // h1 = relu(W1^T @ th + b1)   (bias as C operand)
            short8v h1B[2];
            #pragma unroll
            for (int mt = 0; mt < 4; ++mt) {
                const f32x4 cc = *(const f32x4*)&n1b_l[mt * 16 + quad * 4];
                const f32x4 d = MFMA32(W1f[mt], thB, cc);
                #pragma unroll
                for (int r = 0; r < 4; ++r)
                    h1B[mt >> 1][(mt & 1) * 4 + r] = bft(fmaxf(d[r], 0.f));
            }
            // h2 = relu(W2^T @ h1 + b2)
            short8v h2B[2];
            #pragma unroll
            for (int mt = 0; mt < 4; ++mt) {
                const f32x4 cc = *(const f32x4*)&n2b_l[mt * 16 + quad * 4];
                f32x4 d = MFMA32(W2f[mt][0], h1B[0], cc);
                d = MFMA32(W2f[mt][1], h1B[1], d);
                #pragma unroll
                for (int r = 0; r < 4; ++r)
                    h2B[mt >> 1][(mt & 1) * 4 + r] = bft(fmaxf(d[r], 0.f));
            }
            // heads; lane holds heads quad*4+r for sample col
            f32x4 hd[3];
            #pragma unroll
            for (int mt = 0; mt < 3; ++mt) {
                const f32x4 cc = *(const f32x4*)&hb_l[mt * 16 + quad * 4];
                f32x4 d = MFMA32(Whf[mt][0], h2B[0], cc);
                hd[mt] = MFMA32(Whf[mt][1], h2B[1], d);
            }
            // no-max logsumexp (terms O(1); underflow->0 == reference's 0)
            const float xt = x_l[col * 130 + t];
            float s1 = 0.f, s2 = 0.f;
            #pragma unroll
            for (int r = 0; r < 4; ++r) {
                const bool valid = (quad * 4 + r) < 10;
                const float mu = hd[0][r], sg = hd[1][r], la = hd[2][r];
                const float e1t = __expf(la);
                const float z = (xt - mu) * __expf(-sg);
                const float e2t = __expf(la - sg - fmaf(0.5f * z, z, CST));
                s1 += valid ? e1t : 0.f;
                s2 += valid ? e2t : 0.f;
            }
            s1 += __shfl_xor(s1, 16, 64);  s2 += __shfl_xor(s2, 16, 64);
            s1 += __shfl_xor(s1, 32, 64);  s2 += __shfl_xor(s2, 32, 64);
            res2 += __log2f(s2) - __log2f(s1);

            t = tn;
        }
        if (lane == 0) *(volatile int*)&prog_l[c] = 1 << 30;
        if (lane < 16) part_l[wv][lane] = res2;   // uniform across quads
    }

    __syncthreads();
    if (tid < 16) {
        float s = 0.f;
        #pragma unroll
        for (int w = 0; w < 8; ++w) s += part_l[w][tid];
        out[n0 + tid] = exp2f(s);
    }
}

extern "C" void kernel_launch(void* const* d_in, const int* in_sizes, int n_in,
                              void* d_out, int out_size, void* d_ws, size_t ws_size,
                              hipStream_t stream) {
    wfa_kernel<<<dim3(NN / 16), dim3(512), 0, stream>>>(
        (const float*)d_in[0],  (const float*)d_in[1],  (const float*)d_in[2],
        (const float*)d_in[3],  (const float*)d_in[4],  (const float*)d_in[5],
        (const float*)d_in[6],  (const float*)d_in[7],  (const float*)d_in[8],
        (const float*)d_in[9],  (const float*)d_in[10], (const float*)d_in[11],
        (const float*)d_in[12], (const float*)d_in[13], (const float*)d_in[14],
        (const float*)d_in[15], (const float*)d_in[16], (float*)d_out);
}

// Round 6
// 141.715 us; speedup vs baseline: 1.0581x; 1.0581x over previous
//
#include <hip/hip_runtime.h>

#define DEV __device__ __forceinline__

typedef __attribute__((ext_vector_type(8))) short short8v;
typedef __attribute__((ext_vector_type(4))) float f32x4;

DEV unsigned short bfr(float f) {                 // fp32 -> bf16 RNE (weights)
    unsigned u = __float_as_uint(f);
    return (unsigned short)((u + 0x7fffu + ((u >> 16) & 1u)) >> 16);
}
DEV short bft(float f) { return (short)(__float_as_uint(f) >> 16); } // truncate (activations)
DEV float bf2f(unsigned short h) { return __uint_as_float(((unsigned)h) << 16); }
DEV float frcp(float x) { return __builtin_amdgcn_rcpf(x); }
DEV float ftanh(float x) { float e = __expf(2.0f * x); return 1.0f - 2.0f * frcp(e + 1.0f); }

constexpr int NN = 4096, TT = 128, RING = 32;
#define MFMA32(a, b, c) __builtin_amdgcn_mfma_f32_16x16x32_bf16(a, b, c, 0, 0, 0)

// Lock-free producer/consumer, 512 threads. R5 post-mortem: VGPR stayed 88 =>
// the compiler re-interleaved the 16 MFMAs with the reduction (register-
// pressure-driven), recreating ~8 MFMA-latency wait chains per step. Three
// scanner-latency fixes this round:
//  (1) sched_group_barrier pins the schedule: 16 MFMAs back-to-back, THEN
//      the VALU reduction. Tell: VGPR must jump to ~150 (16 live f32x4).
//  (2) Publish head every 4 steps, not 2: __threadfence_block is
//      s_waitcnt lgkmcnt(0), which was also draining the SAME-step enc
//      prefetch ds_read -- the measured R0(63.5us)->R4(70us) lock-free
//      regression.
//  (3) Wave 4 (shares SIMD0 with the scanner, wv%4 round-robin) is idled:
//      its phi MFMAs stole the SIMD0 matrix pipe (~19cyc each, setprio
//      can't preempt an issued MFMA). Tickets auto-redistribute to the 6
//      consumers on SIMD1-3 (21 items x ~1.1k cyc x 2 waves/SIMD = 46k cyc,
//      well under the scan wall).
// R1-R3 LESSON kept: 512 threads only (1024 => hard 64-VGPR cap => spills).
// R2 LESSON kept: no asm memory clobbers in hot loops.

__global__ __launch_bounds__(512) __attribute__((amdgpu_waves_per_eu(2)))
void wfa_kernel(
    const float* __restrict__ x,
    const float* __restrict__ e1w, const float* __restrict__ e1b,
    const float* __restrict__ e2w, const float* __restrict__ e2b,
    const float* __restrict__ A,
    const float* __restrict__ initw,
    const float* __restrict__ n1w, const float* __restrict__ n1b,
    const float* __restrict__ n2w, const float* __restrict__ n2b,
    const float* __restrict__ muw, const float* __restrict__ mub,
    const float* __restrict__ sgw, const float* __restrict__ sgb,
    const float* __restrict__ alw, const float* __restrict__ alb,
    float* __restrict__ out)
{
    __shared__ __align__(16) unsigned short enc_l[TT * 128];  // [t][n*8+d] bf16, 32KB
    __shared__ __align__(16) float x_l[16 * 130];             // [n][t]
    __shared__ __align__(16) short8v ring_l[RING][64];        // tmp frags, 32KB
    __shared__ __align__(16) float n1b_l[64], n2b_l[64], hb_l[48];
    __shared__ float part_l[8][16];
    __shared__ int head_l;     // items published by scanner
    __shared__ int ticket_l;   // next item index to hand out
    __shared__ int prog_l[7];  // per-consumer: all my ring reads < prog are done

    const int tid = threadIdx.x;
    const int wv = tid >> 6, lane = tid & 63;
    const int quad = lane >> 4, col = lane & 15;
    const int n0 = blockIdx.x * 16;
    const f32x4 z4 = {0.f, 0.f, 0.f, 0.f};

    // ---- stage x + biases + control ----
    for (int i = tid; i < 16 * TT; i += 512)
        x_l[(i >> 7) * 130 + (i & 127)] = x[(n0 + (i >> 7)) * TT + (i & 127)];
    if (tid < 64) { n1b_l[tid] = n1b[tid]; n2b_l[tid] = n2b[tid]; }
    if (tid >= 64 && tid < 112) {
        const int i = tid - 64, mt = i >> 4, k = i & 15;
        hb_l[i] = (k < 10) ? ((mt == 0) ? mub[k] : (mt == 1) ? sgb[k] : alb[k]) : 0.f;
    }
    // prog slot 3 belongs to wave 4, which is idled this round: park at +inf
    if (tid >= 112 && tid < 119) prog_l[tid - 112] = (tid == 115) ? (1 << 30) : 0;
    if (tid == 120) { head_l = 0; ticket_l = 0; }

    __syncthreads();   // x_l + control ready

    // ---- encoder: in-lane rank-1 layer1 + 2 MFMAs; wave wv owns t-tile wv ----
    {
        float e1c[16], e1bc[16];
        #pragma unroll
        for (int kc = 0; kc < 2; ++kc)
            #pragma unroll
            for (int jj = 0; jj < 8; ++jj) {
                const int f = kc * 32 + (jj >> 2) * 16 + quad * 4 + (jj & 3);
                e1c[kc * 8 + jj] = e1w[f];
                e1bc[kc * 8 + jj] = e1b[f];
            }
        short8v E2A[2];   // A[m=d(col<8)][k=h feature, permuted]
        #pragma unroll
        for (int kc = 0; kc < 2; ++kc)
            #pragma unroll
            for (int jj = 0; jj < 8; ++jj)
                E2A[kc][jj] = (short)(col < 8
                    ? bfr(e2w[(kc * 32 + (jj >> 2) * 16 + quad * 4 + (jj & 3)) * 8 + col]) : 0);
        float e2bc[4];
        #pragma unroll
        for (int r = 0; r < 4; ++r) e2bc[r] = (quad < 2) ? e2b[quad * 4 + r] : 0.f;

        const int tbase = wv * 16;
        #pragma unroll 1
        for (int nn = 0; nn < 16; ++nn) {
            const float xs = x_l[nn * 130 + tbase + col];
            short8v eB[2];
            #pragma unroll
            for (int kc = 0; kc < 2; ++kc)
                #pragma unroll
                for (int jj = 0; jj < 8; ++jj)
                    eB[kc][jj] = bft(fmaxf(fmaf(xs, e1c[kc * 8 + jj], e1bc[kc * 8 + jj]), 0.f));
            f32x4 d = MFMA32(E2A[0], eB[0], z4);
            d = MFMA32(E2A[1], eB[1], d);
            if (quad < 2) {
                #pragma unroll
                for (int r = 0; r < 4; ++r)
                    enc_l[(tbase + col) * 128 + nn * 8 + quad * 4 + r] = bfr(ftanh(d[r] + e2bc[r]));
            }
        }
    }
    __syncthreads();   // enc_l ready; last block-wide barrier until epilogue

    if (wv == 0) {
        // =========================== SCANNER ===========================
        short8v A2f[16];   // out m=mt*16+col -> d=mt>>1, j-half=mt&1; k=i (permuted)
        #pragma unroll
        for (int mt = 0; mt < 16; ++mt)
            #pragma unroll
            for (int jj = 0; jj < 8; ++jj)
                A2f[mt][jj] = (short)bfr(
                    A[((jj >> 2) * 16 + quad * 4 + (jj & 3)) * 256 + (mt >> 1) * 32 + (mt & 1) * 16 + col]);

        short8v tmpB;
        #pragma unroll
        for (int jj = 0; jj < 8; ++jj)
            tmpB[jj] = (short)bfr(initw[(jj >> 2) * 16 + quad * 4 + (jj & 3)]);

        asm volatile("s_setprio 2");   // win SIMD0 VALU arbitration

        short8v e8c = *(const short8v*)&enc_l[0 * 128 + col * 8];  // enc[0] for t=1

        #pragma unroll 1
        for (int t = 0; t < TT; ++t) {
            if (t > 0) {
                // prefetch enc[t] (used at t+1); waited only at e8c=e8n
                const short8v e8n = *(const short8v*)&enc_l[t * 128 + col * 8];
                float ev[8];
                #pragma unroll
                for (int d = 0; d < 8; ++d) ev[d] = bf2f((unsigned short)e8c[d]);
                f32x4 D[16];
                #pragma unroll
                for (int m = 0; m < 16; ++m) D[m] = MFMA32(A2f[m], tmpB, z4);
                short8v nt;
                #pragma unroll
                for (int h = 0; h < 2; ++h)
                    #pragma unroll
                    for (int r = 0; r < 4; ++r) {
                        // split 4+4 chains: dep tail ~4 fmaf, not 8
                        float sa = ev[0] * D[h][r];
                        float sb = ev[4] * D[8 + h][r];
                        #pragma unroll
                        for (int d = 1; d < 4; ++d) {
                            sa = fmaf(ev[d],     D[2 * d + h][r],     sa);
                            sb = fmaf(ev[d + 4], D[2 * d + 8 + h][r], sb);
                        }
                        nt[h * 4 + r] = bft(sa + sb);
                    }
                // Pin the schedule the compiler refused in R5: the 16
                // independent MFMAs issue back-to-back (one latency round
                // trip), THEN the VALU reduction. Masks per LLVM
                // SchedGroupMask: MFMA=0x8, VALU=0x2, DS_READ=0x100.
                __builtin_amdgcn_sched_group_barrier(0x100, 1, 0);  // e8n ds_read first
                __builtin_amdgcn_sched_group_barrier(0x008, 16, 0); // 16 MFMA cluster
                __builtin_amdgcn_sched_group_barrier(0x002, 120, 0); // reduction VALU
                tmpB = nt;
                e8c = e8n;
            }
            ring_l[t & (RING - 1)][lane] = tmpB;
            if ((t & 3) == 3) {
                // publish every 4 steps: the lgkmcnt(0) drain here also waits
                // the enc prefetch, so amortize it (R4 lesson: every-2 cost 10%)
                __threadfence_block();                      // commit ring writes
                if (lane == 0) *(volatile int*)&head_l = t + 1;
            }
            if ((t & 7) == 7 && t >= RING - 1 && t < 120) {
                // next 8 writes hit slots of items t+1-RING..t+8-RING:
                // need min(prog) >= t+9-RING
                const int need = t + 9 - RING;
                while (true) {
                    int p = (lane < 7) ? *(volatile int*)&prog_l[lane] : (1 << 30);
                    #pragma unroll
                    for (int s = 1; s < 64; s <<= 1) {
                        const int q = __shfl_xor(p, s, 64);
                        p = (q < p) ? q : p;
                    }
                    if (p >= need) break;
                    __builtin_amdgcn_s_sleep(4);
                }
            }
        }
        if (lane < 16) part_l[0][lane] = 0.f;
    } else if (wv == 4) {
        // Wave 4 shares SIMD0 with the scanner: idle it so its phi MFMAs /
        // VALU bursts never steal the serial chain's pipes. Tickets
        // redistribute to the 6 consumers on SIMD1-3 automatically.
        if (lane < 16) part_l[4][lane] = 0.f;
    } else {
        // ========================== CONSUMERS ==========================
        short8v W1f[4];    // h1 out = mt*16+col, k = th feature (permuted)
        #pragma unroll
        for (int mt = 0; mt < 4; ++mt)
            #pragma unroll
            for (int jj = 0; jj < 8; ++jj)
                W1f[mt][jj] = (short)bfr(n1w[((jj >> 2) * 16 + quad * 4 + (jj & 3)) * 64 + mt * 16 + col]);
        short8v W2f[4][2];
        #pragma unroll
        for (int mt = 0; mt < 4; ++mt)
            #pragma unroll
            for (int kb = 0; kb < 2; ++kb)
                #pragma unroll
                for (int jj = 0; jj < 8; ++jj)
                    W2f[mt][kb][jj] = (short)bfr(
                        n2w[(kb * 32 + (jj >> 2) * 16 + quad * 4 + (jj & 3)) * 64 + mt * 16 + col]);
        short8v Whf[3][2]; // 0=mu,1=sig,2=alpha; out m = head idx (col<10)
        #pragma unroll
        for (int mt = 0; mt < 3; ++mt) {
            const float* Wh = (mt == 0) ? muw : (mt == 1) ? sgw : alw;
            #pragma unroll
            for (int kb = 0; kb < 2; ++kb)
                #pragma unroll
                for (int jj = 0; jj < 8; ++jj)
                    Whf[mt][kb][jj] = (short)(col < 10
                        ? bfr(Wh[(kb * 32 + (jj >> 2) * 16 + quad * 4 + (jj & 3)) * 10 + col]) : 0);
        }

        float res2 = 0.f;
        const float CST = 0.91893853320467274f;
        const int c = wv - 1;

        int t;
        if (lane == 0) { t = atomicAdd(&ticket_l, 1); *(volatile int*)&prog_l[c] = t; }
        t = __shfl(t, 0, 64);

        while (t < TT) {
            // ACQUIRE: orders the ring read after the observed head bump,
            // in compiler and HW, without an all-memory asm clobber.
            while (__hip_atomic_load(&head_l, __ATOMIC_ACQUIRE,
                                     __HIP_MEMORY_SCOPE_WORKGROUP) <= t)
                __builtin_amdgcn_s_sleep(1);
            const short8v tf = ring_l[t & (RING - 1)][lane];
            __threadfence_block();           // ring read complete before prog bump
            int tn;
            if (lane == 0) { tn = atomicAdd(&ticket_l, 1); *(volatile int*)&prog_l[c] = tn; }
            tn = __shfl(tn, 0, 64);

            short8v thB;
            #pragma unroll
            for (int jj = 0; jj < 8; ++jj)
                thB[jj] = bft(ftanh(bf2f((unsigned short)tf[jj])));

            // h1 = relu(W1^T @ th + b1)   (bias as C operand)
            short8v h1B[2];
            #pragma unroll
            for (int mt = 0; mt < 4; ++mt) {
                const f32x4 cc = *(const f32x4*)&n1b_l[mt * 16 + quad * 4];
                const f32x4 d = MFMA32(W1f[mt], thB, cc);
                #pragma unroll
                for (int r = 0; r < 4; ++r)
                    h1B[mt >> 1][(mt & 1) * 4 + r] = bft(fmaxf(d[r], 0.f));
            }
            // h2 = relu(W2^T @ h1 + b2)
            short8v h2B[2];
            #pragma unroll
            for (int mt = 0; mt < 4; ++mt) {
                const f32x4 cc = *(const f32x4*)&n2b_l[mt * 16 + quad * 4];
                f32x4 d = MFMA32(W2f[mt][0], h1B[0], cc);
                d = MFMA32(W2f[mt][1], h1B[1], d);
                #pragma unroll
                for (int r = 0; r < 4; ++r)
                    h2B[mt >> 1][(mt & 1) * 4 + r] = bft(fmaxf(d[r], 0.f));
            }
            // heads; lane holds heads quad*4+r for sample col
            f32x4 hd[3];
            #pragma unroll
            for (int mt = 0; mt < 3; ++mt) {
                const f32x4 cc = *(const f32x4*)&hb_l[mt * 16 + quad * 4];
                f32x4 d = MFMA32(Whf[mt][0], h2B[0], cc);
                hd[mt] = MFMA32(Whf[mt][1], h2B[1], d);
            }
            // no-max logsumexp (terms O(1); underflow->0 == reference's 0)
            const float xt = x_l[col * 130 + t];
            float s1 = 0.f, s2 = 0.f;
            #pragma unroll
            for (int r = 0; r < 4; ++r) {
                const bool valid = (quad * 4 + r) < 10;
                const float mu = hd[0][r], sg = hd[1][r], la = hd[2][r];
                const float e1t = __expf(la);
                const float z = (xt - mu) * __expf(-sg);
                const float e2t = __expf(la - sg - fmaf(0.5f * z, z, CST));
                s1 += valid ? e1t : 0.f;
                s2 += valid ? e2t : 0.f;
            }
            s1 += __shfl_xor(s1, 16, 64);  s2 += __shfl_xor(s2, 16, 64);
            s1 += __shfl_xor(s1, 32, 64);  s2 += __shfl_xor(s2, 32, 64);
            res2 += __log2f(s2) - __log2f(s1);

            t = tn;
        }
        if (lane == 0) *(volatile int*)&prog_l[c] = 1 << 30;
        if (lane < 16) part_l[wv][lane] = res2;   // uniform across quads
    }

    __syncthreads();
    if (tid < 16) {
        float s = 0.f;
        #pragma unroll
        for (int w = 0; w < 8; ++w) s += part_l[w][tid];
        out[n0 + tid] = exp2f(s);
    }
}

extern "C" void kernel_launch(void* const* d_in, const int* in_sizes, int n_in,
                              void* d_out, int out_size, void* d_ws, size_t ws_size,
                              hipStream_t stream) {
    wfa_kernel<<<dim3(NN / 16), dim3(512), 0, stream>>>(
        (const float*)d_in[0],  (const float*)d_in[1],  (const float*)d_in[2],
        (const float*)d_in[3],  (const float*)d_in[4],  (const float*)d_in[5],
        (const float*)d_in[6],  (const float*)d_in[7],  (const float*)d_in[8],
        (const float*)d_in[9],  (const float*)d_in[10], (const float*)d_in[11],
        (const float*)d_in[12], (const float*)d_in[13], (const float*)d_in[14],
        (const float*)d_in[15], (const float*)d_in[16], (float*)d_out);
}